// Round 1
// baseline (144.072 us; speedup 1.0000x reference)
//
#include <hip/hip_runtime.h>
#include <stdint.h>

// Q2Linear int8 path, 2 dispatches — R12: R7 structure + 32x32x32 i8 MFMA + setprio.
//   prep: blocks 0..1023    — per-row quantize x fp32 -> i8 (q = rowmax/127)
//         blocks 1024..5119 — pack w int32 {-2..1} -> i8 (exact, coalesced)
//   q8_gemm: i8 MFMA 32x32x32 (4404 TOPS ceiling vs 3944 for 16x16x64; half the
//            MFMA instructions for the same 12 ds_read_b128/it), tile 64m x 128n,
//            BK=128, 512 blocks = 2/CU (LDS 64.9 KB). A and B staged via
//            global_load_lds(16B) into XOR-swizzled dbuf LDS (0 conflicts; swizzle
//            key row&7 == lane&7 identical for 16x16 and 32x32 read patterns).
//            Scales staged once into padded LDS [n][33]; with 32x32 each lane owns
//            ONE n-column -> single sf load/it. T5 s_setprio(1) wraps the MFMA
//            cluster (2 independent blocks/CU = decorrelated phases, attn-like
//            regime where setprio measured positive).
// Fragment maps (verified conventions): A/B row = lane&31, k-chunk = lane>>5;
// C/D col = lane&31, row = (reg&3) + 8*(reg>>2) + 4*(lane>>5).
// Post-mortem ledger: R8 2-bit B (VALU on MFMA waves) -36%; R9 64x64/4-blk
// (VGPR 256 balloon, 3x HBM re-read) -2.7x; R10 direct-A (latency exposed) -2x;
// R11 = R7 restored. Timed region carries ~83 us of harness poison fills
// (2 x 268 MB @ 41.5 us); kernels are ~60 us of the 143.

#define MM 1024
#define NN 4096
#define KK 4096
#define BK 128

typedef __attribute__((ext_vector_type(4))) int intx4;
typedef __attribute__((ext_vector_type(16))) int intx16;
typedef __attribute__((ext_vector_type(4))) float floatx4;
typedef __attribute__((ext_vector_type(16))) float floatx16;

typedef const __attribute__((address_space(1))) void global_cvoid;
typedef __attribute__((address_space(3))) void lds_void;

// ---- prep: quantize x (blocks < MM) OR pack w -> i8 --------------------------
__global__ __launch_bounds__(256) void prep(const float* __restrict__ x,
                                            const int* __restrict__ wq,
                                            char* __restrict__ xq,
                                            float* __restrict__ qrow,
                                            char* __restrict__ wb) {
    const int tid = threadIdx.x;
    if (blockIdx.x < MM) {
        const int m = blockIdx.x;
        const float* xr = x + (size_t)m * KK;
        floatx4 v[4];
        float amax = 0.f;
#pragma unroll
        for (int c = 0; c < 4; ++c) {
            v[c] = *(const floatx4*)(xr + (c * 256 + tid) * 4);
#pragma unroll
            for (int e = 0; e < 4; ++e) amax = fmaxf(amax, fabsf(v[c][e]));
        }
#pragma unroll
        for (int off = 32; off; off >>= 1) amax = fmaxf(amax, __shfl_down(amax, off));
        __shared__ float wmax[4];
        if ((tid & 63) == 0) wmax[tid >> 6] = amax;
        __syncthreads();
        amax = fmaxf(fmaxf(wmax[0], wmax[1]), fmaxf(wmax[2], wmax[3]));
        amax = fmaxf(amax, 1e-20f);
        const float qinv = 127.0f / amax;
        if (tid == 0) qrow[m] = amax / 127.0f;
#pragma unroll
        for (int c = 0; c < 4; ++c) {
            int p = 0;
#pragma unroll
            for (int e = 0; e < 4; ++e) {
                float r = rintf(v[c][e] * qinv);
                r = fminf(fmaxf(r, -127.f), 127.f);
                p |= ((int)r & 255) << (8 * e);
            }
            *(int*)(xq + (size_t)m * KK + (c * 256 + tid) * 4) = p;
        }
    } else {
        // pack w: fully coalesced (lane-consecutive 16B reads / 4B writes)
        const int blk = blockIdx.x - MM;
#pragma unroll
        for (int c = 0; c < 4; ++c) {
            size_t c4 = (size_t)blk * 1024 + c * 256 + tid;  // intx4-chunk id
            intx4 a = ((const intx4*)wq)[c4];
            ((int*)wb)[c4] = (a[0] & 255) | ((a[1] & 255) << 8) |
                             ((a[2] & 255) << 16) | (a[3] << 24);
        }
    }
}

// ---- GEMM: 64x128 tile, 4 waves (each 64m x 32n), double-buffered LDS --------
__global__ __launch_bounds__(256, 2) void q8_gemm(const char* __restrict__ xq,
                                                  const char* __restrict__ wb,
                                                  const float* __restrict__ qrow,
                                                  const float* __restrict__ scales,
                                                  float* __restrict__ out) {
    __shared__ char As[2][64 * BK];    // 8 KB each
    __shared__ char Bs[2][128 * BK];   // 16 KB each
    __shared__ float Sl[128 * 33];     // scales [n_local][block], +1 pad (16.9 KB)
    // total 64.9 KB -> 2 blocks/CU

    const int tid  = threadIdx.x;
    const int lane = tid & 63;
    const int wave = tid >> 6;
    const int l31  = lane & 31;        // A/B fragment row, C/D col (n)
    const int hi   = lane >> 5;        // k-chunk half selector
    const int sw   = lane & 7;         // swizzle key == row&7 for all read rows
    const int wn   = wave * 32;        // wave's n offset within tile

    // XCD pinning: bid&7 -> XCD; each XCD owns 4 n-tiles (512 cols, 2MB i8 B-strip)
    const int bid = blockIdx.x;
    const int xcd = bid & 7, loc = bid >> 3;   // loc 0..63
    const int nT = xcd * 4 + (loc & 3);        // 0..31
    const int mT = loc >> 2;                   // 0..15
    const int mBase = mT * 64, nBase = nT * 128;

    // staging address permute -> XOR-swizzled LDS tile (verified, 0 conflicts)
    const int rg = lane >> 3;
    const int cs = (lane & 7) ^ rg;
    const char* gA = xq + (size_t)(mBase + wave * 16 + rg) * KK + cs * 16;
    const char* gB = wb + (size_t)(nBase + wave * 32 + rg) * KK + cs * 16;
    const int ldsRowA = wave * 16;
    const int ldsRowB = wave * 32;

    floatx16 fac0, fac1;
#pragma unroll
    for (int r = 0; r < 16; ++r) { fac0[r] = 0.f; fac1[r] = 0.f; }

#define STAGE(BUF, SLAB)                                                        \
    {                                                                           \
        _Pragma("unroll")                                                       \
        for (int t = 0; t < 2; ++t)                                             \
            __builtin_amdgcn_global_load_lds(                                   \
                (global_cvoid*)(gA + (size_t)(t * 8) * KK + (SLAB) * BK),       \
                (lds_void*)&As[BUF][(ldsRowA + t * 8) * BK], 16, 0, 0);         \
        _Pragma("unroll")                                                       \
        for (int t = 0; t < 4; ++t)                                             \
            __builtin_amdgcn_global_load_lds(                                   \
                (global_cvoid*)(gB + (size_t)(t * 8) * KK + (SLAB) * BK),       \
                (lds_void*)&Bs[BUF][(ldsRowB + t * 8) * BK], 16, 0, 0);         \
    }

    // 32x32x32: per kp (K=32 step), av rows l31 / 32+l31, bv row wn+l31,
    // k-chunk (kp*2+hi)^sw. 8 MFMA + 12 ds_read_b128 per it (was 16 + 12).
#define COMPUTE(BUF, SLAB)                                                      \
    {                                                                           \
        const float sf = Sl[(wn + l31) * 33 + (SLAB)];                          \
        intx16 iacc0, iacc1;                                                    \
        __builtin_amdgcn_s_setprio(1);                                          \
        _Pragma("unroll")                                                       \
        for (int kp = 0; kp < 4; ++kp) {                                        \
            const int kc = (((kp * 2) + hi) ^ sw) << 4;                         \
            intx4 av0 = *(const intx4*)&As[BUF][l31 * BK + kc];                 \
            intx4 av1 = *(const intx4*)&As[BUF][(32 + l31) * BK + kc];          \
            intx4 bv  = *(const intx4*)&Bs[BUF][(wn + l31) * BK + kc];          \
            if (kp == 0) {                                                      \
                intx16 z = {0, 0, 0, 0, 0, 0, 0, 0, 0, 0, 0, 0, 0, 0, 0, 0};    \
                iacc0 = __builtin_amdgcn_mfma_i32_32x32x32_i8(av0, bv, z, 0, 0, 0); \
                iacc1 = __builtin_amdgcn_mfma_i32_32x32x32_i8(av1, bv, z, 0, 0, 0); \
            } else {                                                            \
                iacc0 = __builtin_amdgcn_mfma_i32_32x32x32_i8(av0, bv, iacc0, 0, 0, 0); \
                iacc1 = __builtin_amdgcn_mfma_i32_32x32x32_i8(av1, bv, iacc1, 0, 0, 0); \
            }                                                                   \
        }                                                                       \
        __builtin_amdgcn_s_setprio(0);                                          \
        _Pragma("unroll")                                                       \
        for (int r = 0; r < 16; ++r) {                                          \
            fac0[r] += (float)iacc0[r] * sf;                                    \
            fac1[r] += (float)iacc1[r] * sf;                                    \
        }                                                                       \
    }

    STAGE(0, 0)
    // stage scales once: coalesced global read; LDS banks (nl+b)%32 -> 2-way = free
    for (int t = tid; t < 4096; t += 256) {
        int nl = t >> 5, b = t & 31;
        Sl[nl * 33 + b] = scales[(size_t)(nBase + nl) * 32 + b];
    }
    __syncthreads();

    const int NIT = KK / BK;  // 32
    for (int it = 0; it < NIT; it += 2) {
        if (it + 1 < NIT) STAGE(1, it + 1)
        COMPUTE(0, it)
        __syncthreads();
        if (it + 2 < NIT) STAGE(0, it + 2)
        COMPUTE(1, it + 1)
        __syncthreads();
    }

    // epilogue: C/D col = lane&31 (n), row = (reg&3)+8*(reg>>2)+4*hi (m); fold q[m]
#pragma unroll
    for (int g = 0; g < 4; ++g) {
        floatx4 qv0 = *(const floatx4*)(qrow + mBase + g * 8 + hi * 4);
        floatx4 qv1 = *(const floatx4*)(qrow + mBase + 32 + g * 8 + hi * 4);
#pragma unroll
        for (int r = 0; r < 4; ++r) {
            const int m0 = mBase + g * 8 + hi * 4 + r;
            out[(size_t)m0 * NN + nBase + wn + l31]        = fac0[g * 4 + r] * qv0[r];
            out[(size_t)(m0 + 32) * NN + nBase + wn + l31] = fac1[g * 4 + r] * qv1[r];
        }
    }
#undef STAGE
#undef COMPUTE
}

extern "C" void kernel_launch(void* const* d_in, const int* in_sizes, int n_in,
                              void* d_out, int out_size, void* d_ws, size_t ws_size,
                              hipStream_t stream) {
    const float* x      = (const float*)d_in[0];
    const int*   wq     = (const int*)d_in[1];
    const float* scales = (const float*)d_in[2];
    float*       out    = (float*)d_out;

    char*  xq   = (char*)d_ws;                                   // 4 MB
    float* qrow = (float*)((char*)d_ws + (size_t)MM * KK);       // 4 KB
    char*  wb   = (char*)d_ws + (size_t)MM * KK + 4096;          // 16.8 MB

    prep<<<MM + (size_t)NN * KK / 16 / 256, 256, 0, stream>>>(x, wq, xq, qrow, wb);
    q8_gemm<<<(MM / 64) * (NN / 128), 256, 0, stream>>>(xq, wb, qrow, scales, out);
}